// Round 1
// 1664.480 us; speedup vs baseline: 1.1546x; 1.1546x over previous
//
#include <hip/hip_runtime.h>
#include <hip/hip_bf16.h>

// Problem constants (from reference setup_inputs)
#define T_STEPS 100
#define BATCH   16
#define H_IN    260
#define W_IN    346
#define H_P     65      // H_IN/4
#define W_P     86      // W_IN/4 (crops 2 cols)
#define HW      (H_P * W_P)          // 5590
#define NPIX    (BATCH * HW)         // 89440
#define NIMG    (T_STEPS * BATCH)    // 1600
#define CHW_IN  (2 * H_IN * W_IN)

// ---------------------------------------------------------------------------
// Kernel A: fused AvgPool(4) + 3x3 conv (2ch -> 1ch) + ReLU, all in float64.
// 32x32 output tile per block (256 threads, 4 outputs/thread); pooled 34x34x2
// halo tile staged in LDS as double. float2 global loads (guaranteed 8B-aligned
// since row stride 346 floats is even; 16B alignment does NOT hold per row).
// ---------------------------------------------------------------------------
__global__ __launch_bounds__(256) void pool_exc_f64(const float* __restrict__ x,
                                                    const float* __restrict__ ew,
                                                    double* __restrict__ exc) {
    const int n   = blockIdx.z;                  // image index t*B+b
    const int ti0 = blockIdx.y * 32;
    const int tj0 = blockIdx.x * 32;

    __shared__ double p[2][34][35];              // pooled tile (+1 pad)
    __shared__ double wsm[18];                   // exc_w (1,2,3,3)

    const int tid = threadIdx.x;
    if (tid < 18) wsm[tid] = (double)ew[tid];

    const float* xb = x + (size_t)n * CHW_IN;

    for (int idx = tid; idx < 2 * 34 * 34; idx += 256) {
        const int c  = idx / (34 * 34);
        const int r  = idx % (34 * 34);
        const int ri = r / 34;
        const int rj = r % 34;
        const int pi = ti0 - 1 + ri;             // pooled row (SAME pad for 3x3)
        const int pj = tj0 - 1 + rj;
        double v = 0.0;
        if (pi >= 0 && pi < H_P && pj >= 0 && pj < W_P) {
            const float* base = xb + (size_t)c * (H_IN * W_IN) + (4 * pi) * W_IN + 4 * pj;
            double s = 0.0;
            #pragma unroll
            for (int di = 0; di < 4; ++di) {
                const float2 a = *reinterpret_cast<const float2*>(base + di * W_IN);
                const float2 b = *reinterpret_cast<const float2*>(base + di * W_IN + 2);
                s += (double)a.x + (double)a.y + (double)b.x + (double)b.y;
            }
            v = s * 0.0625;                      // mean over 16 (exact pow2)
        }
        p[c][ri][rj] = v;
    }
    __syncthreads();

    const int tx  = tid & 31;
    const int ty0 = tid >> 5;                    // 0..7
    #pragma unroll
    for (int q = 0; q < 4; ++q) {
        const int ly = ty0 + q * 8;              // local output row 0..31
        const int i  = ti0 + ly;
        const int j  = tj0 + tx;
        if (i < H_P && j < W_P) {
            double acc = 0.0;
            #pragma unroll
            for (int c = 0; c < 2; ++c)
                #pragma unroll
                for (int ky = 0; ky < 3; ++ky)
                    #pragma unroll
                    for (int kx = 0; kx < 3; ++kx)
                        acc += p[c][ly + ky][tx + kx] * wsm[c * 9 + ky * 3 + kx];
            exc[(size_t)n * HW + i * W_P + j] = (acc > 0.0) ? acc : 0.0;  // ReLU
        }
    }
}

// ---------------------------------------------------------------------------
// Kernel B: zero the f64 accumulators (d_ws is poisoned 0xAA every call)
// ---------------------------------------------------------------------------
__global__ void init_acc(double* __restrict__ acc) {
    const int n = blockIdx.x * 256 + threadIdx.x;
    if (n < 2 * NIMG) acc[n] = 0.0;
}

// ---------------------------------------------------------------------------
// Kernel C: 7x7 conv of exc[t-1] (SAME pad, zeros at t=0) + lgmd = exc + inh,
// fused with the per-(t,b) relu(lgmd) partial sum (net_exc does NOT depend on
// the LIF scan). Massively parallel: 9 blocks per frame x 1600 frames.
// 32x32 output tile, 38x38 f64 halo staged in LDS.
// ---------------------------------------------------------------------------
__global__ __launch_bounds__(256) void inh_lgmd(const double* __restrict__ exc,
                                                const float* __restrict__ iw,
                                                double* __restrict__ lgmd,
                                                double* __restrict__ accn) {
    const int n   = blockIdx.z;                  // frame index t*B+b
    const int t   = n / BATCH;
    const int ti0 = blockIdx.y * 32;
    const int tj0 = blockIdx.x * 32;

    __shared__ double e[38][39];                 // halo tile (+1 pad)
    __shared__ double wsm[49];                   // inh_w (1,1,7,7)
    __shared__ double sred[4];

    const int tid = threadIdx.x;
    if (tid < 49) wsm[tid] = (double)iw[tid];

    // Stage exc[t-1] halo (zeros at t==0 and outside the image -> SAME pad)
    const double* ep = exc + (size_t)(n - BATCH) * HW;   // only deref'd if t>0
    for (int idx = tid; idx < 38 * 38; idx += 256) {
        const int ri = idx / 38;
        const int rj = idx % 38;
        const int ii = ti0 - 3 + ri;
        const int jj = tj0 - 3 + rj;
        double v = 0.0;
        if (t > 0 && (unsigned)ii < (unsigned)H_P && (unsigned)jj < (unsigned)W_P)
            v = ep[ii * W_P + jj];
        e[ri][rj] = v;
    }
    __syncthreads();

    const double* ec = exc  + (size_t)n * HW;
    double*       lp = lgmd + (size_t)n * HW;

    const int tx  = tid & 31;
    const int ty0 = tid >> 5;                    // 0..7
    double psum = 0.0;                           // relu(lgmd) partial
    #pragma unroll
    for (int q = 0; q < 4; ++q) {
        const int ly = ty0 + q * 8;              // local output row 0..31
        const int i  = ti0 + ly;
        const int j  = tj0 + tx;
        if (i < H_P && j < W_P) {
            double acc = 0.0;
            #pragma unroll
            for (int ky = 0; ky < 7; ++ky)
                #pragma unroll
                for (int kx = 0; kx < 7; ++kx)
                    acc += e[ly + ky][tx + kx] * wsm[ky * 7 + kx];
            const double lg = ec[i * W_P + j] + acc;
            lp[i * W_P + j] = lg;
            psum += (lg > 0.0) ? lg : 0.0;
        }
    }

    // block-reduce psum, one f64 atomic per block (9 per frame)
    #pragma unroll
    for (int off = 32; off > 0; off >>= 1) psum += __shfl_down(psum, off);
    if ((tid & 63) == 0) sred[tid >> 6] = psum;
    __syncthreads();
    if (tid == 0) atomicAdd(&accn[n], sred[0] + sred[1] + sred[2] + sred[3]);
}

// ---------------------------------------------------------------------------
// Kernel D: pointwise LIF scan. One thread per (b, pixel), persistent over t.
// Only the v-recurrence is serial; lgmd loads are independent across t so the
// compiler can issue them ahead of the chain. No __syncthreads at all: the
// dcmd partial is a wave-level shuffle reduce + one f64 atomic per wave per t.
// ---------------------------------------------------------------------------
__global__ __launch_bounds__(256) void lif_scan(const double* __restrict__ lgmd,
                                                const float* __restrict__ dw,
                                                float* __restrict__ spikes,
                                                double* __restrict__ accd) {
    const int b = blockIdx.y;
    const int p = blockIdx.x * 256 + threadIdx.x;
    const bool valid = (p < HW);
    const int pc = valid ? p : 0;

    const double wd = valid ? (double)dw[pc] : 0.0;
    const size_t stride = (size_t)BATCH * HW;    // == NPIX; same for lgmd & spikes
    const double* lp = lgmd   + (size_t)b * HW + pc;
    float*        sp = spikes + (size_t)b * HW + pc;

    double v = 0.0;
    #pragma unroll 2
    for (int t = 0; t < T_STEPS; ++t) {
        const double lgraw = lp[(size_t)t * stride];   // in-bounds even if !valid (pc=0)
        const double lg = valid ? lgraw : 0.0;

        // LIF: v += (x - v)/2; spike at v>=0.5; hard reset to 0
        v = v + (lg - v) * 0.5;
        const double s = (v >= 0.5) ? 1.0 : 0.0;
        v = (s != 0.0) ? 0.0 : v;

        if (valid) sp[(size_t)t * stride] = (float)s;

        // dcmd partial: wave-reduce s*wd (wd==0 for invalid lanes)
        double pd = s * wd;
        #pragma unroll
        for (int off = 32; off > 0; off >>= 1) pd += __shfl_down(pd, off);
        if ((threadIdx.x & 63) == 0) atomicAdd(&accd[t * BATCH + b], pd);
    }
}

// ---------------------------------------------------------------------------
// Kernel E: cast accumulators to the fp32 outputs
// ---------------------------------------------------------------------------
__global__ void finalize(const double* __restrict__ accd,
                         const double* __restrict__ accn,
                         float* __restrict__ dcmd,
                         float* __restrict__ ne) {
    const int n = blockIdx.x * 256 + threadIdx.x;
    if (n < NIMG) {
        dcmd[n] = (float)accd[n];
        ne[n]   = (float)(accn[n] / (double)HW);
    }
}

// ---------------------------------------------------------------------------
extern "C" void kernel_launch(void* const* d_in, const int* in_sizes, int n_in,
                              void* d_out, int out_size, void* d_ws, size_t ws_size,
                              hipStream_t stream) {
    const float* x  = (const float*)d_in[0];   // (100,16,2,260,346) fp32
    const float* ew = (const float*)d_in[1];   // (1,2,3,3)
    const float* iw = (const float*)d_in[2];   // (1,1,7,7)
    const float* dw = (const float*)d_in[3];   // (1,1,65,86)

    float* out    = (float*)d_out;
    float* dcmd   = out;                                   // (100,16)
    float* spikes = out + NIMG;                            // (100,16,1,65,86)
    float* ne     = out + NIMG + (size_t)T_STEPS * NPIX;   // (100,16)

    // ws: exc f64 (71.55 MB) + lgmd f64 (71.55 MB) + accd/accn (3200 f64)
    double* exc  = (double*)d_ws;
    double* lgmd = exc  + (size_t)T_STEPS * NPIX;
    double* accd = lgmd + (size_t)T_STEPS * NPIX;
    double* accn = accd + NIMG;

    dim3 gA((W_P + 31) / 32, (H_P + 31) / 32, NIMG);       // 3 x 3 x 1600
    pool_exc_f64<<<gA, 256, 0, stream>>>(x, ew, exc);

    init_acc<<<(2 * NIMG + 255) / 256, 256, 0, stream>>>(accd);

    dim3 gB((W_P + 31) / 32, (H_P + 31) / 32, NIMG);       // 3 x 3 x 1600
    inh_lgmd<<<gB, 256, 0, stream>>>(exc, iw, lgmd, accn);

    dim3 gC((HW + 255) / 256, BATCH);                      // 22 x 16
    lif_scan<<<gC, 256, 0, stream>>>(lgmd, dw, spikes, accd);

    finalize<<<(NIMG + 255) / 256, 256, 0, stream>>>(accd, accn, dcmd, ne);
}